// Round 2
// baseline (281.613 us; speedup 1.0000x reference)
//
#include <hip/hip_runtime.h>
#include <hip/hip_bf16.h>

// ChebyKANLinear: y[b,j] = sum_i sum_k T_k(tanh(x[b,i])) * C[i,j,k]
//   x: (16384, 512) f32; C: (512, 512, 9) f32; y: (16384, 512) f32
// GEMM view: M=16384, N=512, K=4608 (kflat = k*512 + i), A generated on the fly.
// v2: cooperative basis->LDS (computed once per block, no spills), BM=128 BN=128,
//     8 waves (wave tile 32x64), grid 512 blocks = 2 blocks/CU, 4 waves/SIMD.

typedef __bf16 bf16x8 __attribute__((ext_vector_type(8)));
typedef float  f32x4  __attribute__((ext_vector_type(4)));

#define DIM  512
#define KDEG 9
#define KF   (DIM * KDEG)   // 4608
#define BM   128
#define BN   128
#define ASTRIDE 264         // 8 k-slices * 32 i + 8 pad (bf16); 528B rows -> 16B-slot stagger

// ---------------- pack kernel: C[i][j][k] -> W[j][k*512 + i] (bf16) -------------
__global__ void pack_w_kernel(const float* __restrict__ coeffs,
                              __bf16* __restrict__ W) {
    int tid = blockIdx.x * blockDim.x + threadIdx.x;   // 512*512 threads
    int i = tid & (DIM - 1);
    int j = tid >> 9;
    const float* src = coeffs + ((size_t)i * DIM + j) * KDEG;  // contiguous 9 floats
    __bf16* dst = W + (size_t)j * KF + i;
#pragma unroll
    for (int k = 0; k < KDEG; ++k) {
        dst[k * DIM] = (__bf16)src[k];
    }
}

// ---------------- fused Chebyshev-basis + MFMA GEMM -----------------------------
__global__ __launch_bounds__(512, 4) void cheby_gemm_kernel(
    const float* __restrict__ x,
    const __bf16* __restrict__ W,
    float* __restrict__ out)
{
    __shared__ __bf16 A_lds[BM * ASTRIDE];   // 67.6 KB

    const int tid  = threadIdx.x;
    const int lane = tid & 63;
    const int wid  = tid >> 6;     // 0..7
    const int wr   = wid & 3;      // 0..3  row group of 32
    const int wc   = wid >> 2;     // 0..1  col group of 64
    const int l15  = lane & 15;
    const int l4   = lane >> 4;    // 0..3
    const int bm   = blockIdx.y * BM;
    const int bn   = blockIdx.x * BN;

    // basis-compute mapping: each thread owns 8 consecutive i of one row
    const int crow  = tid >> 2;           // 0..127
    const int cisub = (tid & 3) * 8;      // 0,8,16,24
    const float* xptr = x + (size_t)(bm + crow) * DIM + cisub;
    __bf16* aw = A_lds + crow * ASTRIDE + cisub;

    // B pointers: one per n-frag; lane offset folded in
    const __bf16* wcol[4];
#pragma unroll
    for (int nf = 0; nf < 4; ++nf)
        wcol[nf] = W + (size_t)(bn + wc * 64 + nf * 16 + l15) * KF + l4 * 8;

    // A-frag read base (mf=0); mf=1 adds 16*ASTRIDE (immediate)
    const __bf16* ard = A_lds + (wr * 32 + l15) * ASTRIDE + l4 * 8;

    f32x4 acc[2][4] = {};

    bf16x8 aone;
#pragma unroll
    for (int e = 0; e < 8; ++e) aone[e] = (__bf16)1.0f;

    for (int ic = 0; ic < 16; ++ic) {
        // ---- phase 1: cooperative basis compute -> LDS (k = 1..8) ----
        {
            f32x4 x0 = *reinterpret_cast<const f32x4*>(xptr + ic * 32);
            f32x4 x1 = *reinterpret_cast<const f32x4*>(xptr + ic * 32 + 4);
            float t2[8], Tk[8], Tm[8];
#pragma unroll
            for (int e = 0; e < 8; ++e) {
                float xv = (e < 4) ? x0[e] : x1[e - 4];
                float p  = __builtin_amdgcn_exp2f(xv * 2.8853900817779268f);
                float t  = 1.0f - 2.0f * __builtin_amdgcn_rcpf(p + 1.0f);
                Tk[e] = t;          // T_1
                t2[e] = t + t;
                Tm[e] = 1.0f;       // T_0
            }
#pragma unroll
            for (int k = 1; k < KDEG; ++k) {
                bf16x8 v;
#pragma unroll
                for (int e = 0; e < 8; ++e) v[e] = (__bf16)Tk[e];
                *reinterpret_cast<bf16x8*>(aw + (k - 1) * 32) = v;
                if (k < KDEG - 1) {
#pragma unroll
                    for (int e = 0; e < 8; ++e) {
                        float Tn = __builtin_fmaf(t2[e], Tk[e], -Tm[e]);
                        Tm[e] = Tk[e];
                        Tk[e] = Tn;
                    }
                }
            }
        }
        __syncthreads();

        // ---- phase 2: MFMA over 9 k-slices of this i-chunk ----
#pragma unroll
        for (int k = 0; k < KDEG; ++k) {
            bf16x8 b[4];
#pragma unroll
            for (int nf = 0; nf < 4; ++nf)
                b[nf] = *reinterpret_cast<const bf16x8*>(wcol[nf] + k * DIM + ic * 32);

            bf16x8 a0, a1;
            if (k == 0) {
                a0 = aone; a1 = aone;
            } else {
                a0 = *reinterpret_cast<const bf16x8*>(ard + (k - 1) * 32);
                a1 = *reinterpret_cast<const bf16x8*>(ard + 16 * ASTRIDE + (k - 1) * 32);
            }
#pragma unroll
            for (int nf = 0; nf < 4; ++nf) {
                acc[0][nf] = __builtin_amdgcn_mfma_f32_16x16x32_bf16(a0, b[nf], acc[0][nf], 0, 0, 0);
                acc[1][nf] = __builtin_amdgcn_mfma_f32_16x16x32_bf16(a1, b[nf], acc[1][nf], 0, 0, 0);
            }
        }
        __syncthreads();
    }

    // ---- epilogue: C/D layout col=lane&15, row=(lane>>4)*4+r ----
#pragma unroll
    for (int mf = 0; mf < 2; ++mf)
#pragma unroll
        for (int r = 0; r < 4; ++r) {
            int row = bm + wr * 32 + mf * 16 + l4 * 4 + r;
            float* orow = out + (size_t)row * DIM + bn + wc * 64 + l15;
#pragma unroll
            for (int nf = 0; nf < 4; ++nf)
                orow[nf * 16] = acc[mf][nf][r];
        }
}

extern "C" void kernel_launch(void* const* d_in, const int* in_sizes, int n_in,
                              void* d_out, int out_size, void* d_ws, size_t ws_size,
                              hipStream_t stream) {
    const float* x      = (const float*)d_in[0];   // (16384, 512)
    const float* coeffs = (const float*)d_in[1];   // (512, 512, 9)
    float* out          = (float*)d_out;           // (16384, 512)
    __bf16* W           = (__bf16*)d_ws;           // 512*4608 bf16 = 4.7MB

    pack_w_kernel<<<(DIM * DIM) / 256, 256, 0, stream>>>(coeffs, W);

    // grid = (N/BN, M/BM) = (4, 128) = 512 blocks = 2 per CU
    cheby_gemm_kernel<<<dim3(DIM / BN, 16384 / BM), 512, 0, stream>>>(x, W, out);
}

// Round 3
// 103.107 us; speedup vs baseline: 2.7313x; 2.7313x over previous
//
#include <hip/hip_runtime.h>
#include <hip/hip_bf16.h>

// ChebyKANLinear: y[b,j] = sum_i sum_k T_k(tanh(x[b,i])) * C[i,j,k]
//   x: (16384, 512) f32; C: (512, 512, 9) f32; y: (16384, 512) f32
// GEMM: M=16384, N=512, K=4608 (kflat = k*512 + i).
// v3 (m97-style): B double-buffered in LDS via global_load_lds (staged once per
// block); A (Chebyshev basis) generated in registers in exact MFMA fragment
// layout, zero in-block redundancy. 8 waves = 8(m) x 1(n); wave tile 16x128.
// BM=128, BN=128, BK=32 (one k-slice per step), 1 barrier/step.

typedef __bf16 bf16x8 __attribute__((ext_vector_type(8)));
typedef float  f32x4  __attribute__((ext_vector_type(4)));

#define DIM  512
#define KDEG 9
#define KF   (DIM * KDEG)   // 4608
#define BM   128
#define BN   128
#define NIC  16             // 512 / 32 i-chunks

// ---------------- pack kernel: C[i][j][k] -> W[j][k*512 + i] (bf16) -------------
__global__ void pack_w_kernel(const float* __restrict__ coeffs,
                              __bf16* __restrict__ W) {
    int tid = blockIdx.x * blockDim.x + threadIdx.x;   // 512*512 threads
    int i = tid & (DIM - 1);
    int j = tid >> 9;
    const float* src = coeffs + ((size_t)i * DIM + j) * KDEG;  // contiguous 9 floats
    __bf16* dst = W + (size_t)j * KF + i;
#pragma unroll
    for (int k = 0; k < KDEG; ++k) {
        dst[k * DIM] = (__bf16)src[k];   // consecutive i -> contiguous bf16 writes
    }
}

// ---------------- fused Chebyshev-basis + MFMA GEMM -----------------------------
__global__ __launch_bounds__(512, 4) void cheby_gemm_kernel(
    const float* __restrict__ x,
    const __bf16* __restrict__ W,
    float* __restrict__ out)
{
    // B tile double buffer: [buf][j_local (BN rows)][32 k-elems], 64B rows -> 16KB
    __shared__ __bf16 Bl[2][BN][32];

    const int tid  = threadIdx.x;
    const int lane = tid & 63;
    const int wid  = tid >> 6;     // 0..7  (m-group of 16 rows)
    const int l15  = lane & 15;
    const int l4   = lane >> 4;    // 0..3
    const int bm   = blockIdx.y * BM;
    const int bn   = blockIdx.x * BN;

    // staging map: thread t loads 16B: row j_local = t>>2, 16B-seg = t&3
    const __bf16* wsrc = W + (size_t)(bn + (tid >> 2)) * KF + (tid & 3) * 8;
    __bf16* ldst0 = &Bl[0][0][0] + tid * 8;   // linear: base + t*16B
    __bf16* ldst1 = &Bl[1][0][0] + tid * 8;

    // A: this thread's x row, fragment-aligned (lane l15 = row, l4 = k-chunk)
    const float* xrow = x + (size_t)(bm + wid * 16 + l15) * DIM + l4 * 8;

    // B frag read base: Bl[buf][nf*16 + l15][l4*8]
    const int boff = l15 * 32 + l4 * 8;

    f32x4 acc[8] = {};   // nf = 0..7 (wave covers all 128 cols)

    // prologue: stage (ic=0, k=0) into buf 0
    __builtin_amdgcn_global_load_lds(wsrc, ldst0, 16, 0, 0);

    f32x4 xa = *reinterpret_cast<const f32x4*>(xrow);
    f32x4 xb = *reinterpret_cast<const f32x4*>(xrow + 4);

    int cur = 0;
    for (int ic = 0; ic < NIC; ++ic) {
        // prefetch next ic's x (used 9 steps later)
        f32x4 nxa, nxb;
        if (ic + 1 < NIC) {
            nxa = *reinterpret_cast<const f32x4*>(xrow + (ic + 1) * 32);
            nxb = *reinterpret_cast<const f32x4*>(xrow + (ic + 1) * 32 + 4);
        }

        // basis init: t = tanh(x) = 1 - 2/(exp2(2*log2e*x)+1)
        float t2[8], Tk[8], Tm[8];
#pragma unroll
        for (int e = 0; e < 8; ++e) {
            float xv = (e < 4) ? xa[e] : xb[e - 4];
            float p  = __builtin_amdgcn_exp2f(xv * 2.8853900817779268f);
            float t  = 1.0f - 2.0f * __builtin_amdgcn_rcpf(p + 1.0f);
            Tk[e] = t;          // T_1
            t2[e] = t + t;
            Tm[e] = 1.0f;       // T_0
        }

#pragma unroll
        for (int k = 0; k < KDEG; ++k) {
            __syncthreads();   // staging of current buf complete; prev reads done

            // stage next step into the other buffer
            if ((k < KDEG - 1) || (ic + 1 < NIC)) {
                const int nic = (k < KDEG - 1) ? ic : ic + 1;
                const int nk  = (k < KDEG - 1) ? k + 1 : 0;
                __builtin_amdgcn_global_load_lds(wsrc + nk * DIM + nic * 32,
                                                 cur ? ldst0 : ldst1, 16, 0, 0);
            }

            // A fragment for this k
            bf16x8 af;
            if (k == 0) {
#pragma unroll
                for (int e = 0; e < 8; ++e) af[e] = (__bf16)1.0f;   // T_0
            } else {
#pragma unroll
                for (int e = 0; e < 8; ++e) af[e] = (__bf16)Tk[e];
                if (k < KDEG - 1) {
#pragma unroll
                    for (int e = 0; e < 8; ++e) {
                        float Tn = __builtin_fmaf(t2[e], Tk[e], -Tm[e]);
                        Tm[e] = Tk[e];
                        Tk[e] = Tn;
                    }
                }
            }

            // B frags from LDS + MFMA
            const __bf16* bbase = &Bl[cur][0][0] + boff;
#pragma unroll
            for (int nf = 0; nf < 8; ++nf) {
                bf16x8 b = *reinterpret_cast<const bf16x8*>(bbase + nf * 16 * 32);
                acc[nf] = __builtin_amdgcn_mfma_f32_16x16x32_bf16(af, b, acc[nf], 0, 0, 0);
            }
            cur ^= 1;
        }
        xa = nxa; xb = nxb;
    }

    // epilogue: C/D layout col=lane&15, row=(lane>>4)*4+r
#pragma unroll
    for (int r = 0; r < 4; ++r) {
        const int row = bm + wid * 16 + l4 * 4 + r;
        float* orow = out + (size_t)row * DIM + bn + l15;
#pragma unroll
        for (int nf = 0; nf < 8; ++nf)
            orow[nf * 16] = acc[nf][r];
    }
}

extern "C" void kernel_launch(void* const* d_in, const int* in_sizes, int n_in,
                              void* d_out, int out_size, void* d_ws, size_t ws_size,
                              hipStream_t stream) {
    const float* x      = (const float*)d_in[0];   // (16384, 512)
    const float* coeffs = (const float*)d_in[1];   // (512, 512, 9)
    float* out          = (float*)d_out;           // (16384, 512)
    __bf16* W           = (__bf16*)d_ws;           // 512*4608 bf16 = 4.7MB

    pack_w_kernel<<<(DIM * DIM) / 256, 256, 0, stream>>>(coeffs, W);

    // grid = (N/BN, M/BM) = (4, 128) = 512 blocks = 2 per CU
    cheby_gemm_kernel<<<dim3(DIM / BN, 16384 / BM), 512, 0, stream>>>(x, W, out);
}